// Round 11
// baseline (630.977 us; speedup 1.0000x reference)
//
#include <hip/hip_runtime.h>
#include <hip/hip_bf16.h>

// SlicedLMHead: logits[2048][32000] = H[2048][4096] @ W[32000][4096]^T + bias
// Round 11: FRAGMENT-LINEAR LDS. cvt passes emit H,W in MFMA-fragment order
// (each 1KB fragment = 64 lanes x 16B contiguous). Staging copies linear 16KB
// regions; every ds_read_b128 is base+frag*1024+lane*16 (lane-linear, bank-
// conflict-free by construction, zero swizzle math). Schedule/ledger = R10
// verbatim (8-phase/2-tile, counted vmcnt(2) drain->barrier->read, lgkm 4/8/0).

typedef __attribute__((ext_vector_type(8))) short bhalf8;   // 8 bf16
typedef __attribute__((ext_vector_type(4))) float f32x4;    // MFMA acc
typedef __attribute__((ext_vector_type(8))) unsigned short us8;

#define M_DIM 2048
#define N_DIM 32000
#define K_DIM 4096
#define BM 256
#define BN 256
#define BK 64
#define NT (K_DIM / BK)       // 64 K-tiles
#define MBLKS (M_DIM / BM)    // 8
#define NBLKS (N_DIM / BN)    // 125
#define NWG (MBLKS * NBLKS)   // 1000, divisible by 8

#define W_ELEMS ((size_t)N_DIM * K_DIM)   // 131,072,000
#define H_ELEMS ((size_t)M_DIM * K_DIM)   // 8,388,608
#define WS_NEEDED ((W_ELEMS + H_ELEMS) * 2)

#define GLOAD_LDS16(g, l) \
    __builtin_amdgcn_global_load_lds( \
        (const __attribute__((address_space(1))) unsigned int*)(g), \
        (__attribute__((address_space(3))) unsigned int*)(l), 16, 0, 0)

__device__ __forceinline__ unsigned short f2bf_rn(float f) {
    unsigned int u = __float_as_uint(f);
    u += 0x7FFFu + ((u >> 16) & 1u);
    return (unsigned short)(u >> 16);
}

// ---------------- W: fp32 -> bf16 fragment-linear ----------------
// chunk c = ((nblk*2 + h)*64 + t)*16 + f, f = wcbit*8 + j*2 + kk (256000 chunks)
// Wf[c*512 + lane*8 + e] = bf16( W[nblk*256+h*128+wcbit*64+j*16+(lane&15)]
//                                 [t*64+kk*32+(lane>>4)*8+e] )
__global__ __launch_bounds__(256)
void cvt_w_frag(const float* __restrict__ w, unsigned short* __restrict__ wn) {
    const int lane = threadIdx.x & 63;
    const int nwav = gridDim.x * 4;
    const int l15  = lane & 15;
    const int l4g  = (lane >> 4) * 8;
    for (int c = blockIdx.x * 4 + (threadIdx.x >> 6); c < 256000; c += nwav) {
        const int f   = c & 15;
        const int t   = (c >> 4) & 63;
        const int hh  = (c >> 10) & 1;
        const int nb  = c >> 11;
        const int kk  = f & 1;
        const int j   = (f >> 1) & 3;
        const int wcb = f >> 3;
        const int row = nb * 256 + hh * 128 + wcb * 64 + j * 16 + l15;
        const int k   = t * 64 + kk * 32 + l4g;
        const float* s = w + (size_t)row * K_DIM + k;
        const float4 v0 = *(const float4*)s;
        const float4 v1 = *(const float4*)(s + 4);
        us8 p;
        p[0] = f2bf_rn(v0.x); p[1] = f2bf_rn(v0.y);
        p[2] = f2bf_rn(v0.z); p[3] = f2bf_rn(v0.w);
        p[4] = f2bf_rn(v1.x); p[5] = f2bf_rn(v1.y);
        p[6] = f2bf_rn(v1.z); p[7] = f2bf_rn(v1.w);
        *(us8*)(wn + (size_t)c * 512 + lane * 8) = p;
    }
}

// ---------------- H: fp32 -> bf16 fragment-linear ----------------
// chunk c = ((mblk*2 + h)*64 + t)*16 + f, f = i*2 + kk (16384 chunks)
// Hf[c*512 + lane*8 + e] = bf16( H[mblk*256+h*128+i*16+(lane&15)]
//                                 [t*64+kk*32+(lane>>4)*8+e] )
__global__ __launch_bounds__(256)
void cvt_h_frag(const float* __restrict__ h, unsigned short* __restrict__ hn) {
    const int lane = threadIdx.x & 63;
    const int nwav = gridDim.x * 4;
    const int l15  = lane & 15;
    const int l4g  = (lane >> 4) * 8;
    for (int c = blockIdx.x * 4 + (threadIdx.x >> 6); c < 16384; c += nwav) {
        const int f  = c & 15;
        const int t  = (c >> 4) & 63;
        const int hh = (c >> 10) & 1;
        const int mb = c >> 11;
        const int kk = f & 1;
        const int i  = f >> 1;
        const int row = mb * 256 + hh * 128 + i * 16 + l15;
        const int k   = t * 64 + kk * 32 + l4g;
        const float* s = h + (size_t)row * K_DIM + k;
        const float4 v0 = *(const float4*)s;
        const float4 v1 = *(const float4*)(s + 4);
        us8 p;
        p[0] = f2bf_rn(v0.x); p[1] = f2bf_rn(v0.y);
        p[2] = f2bf_rn(v0.z); p[3] = f2bf_rn(v0.w);
        p[4] = f2bf_rn(v1.x); p[5] = f2bf_rn(v1.y);
        p[6] = f2bf_rn(v1.z); p[7] = f2bf_rn(v1.w);
        *(us8*)(hn + (size_t)c * 512 + lane * 8) = p;
    }
}

// ---------------- 256^2 bf16 GEMM, 8-phase / 2-tile, fragment-linear ----------------
// LDS (elems): A half (buf,h) at (buf*2+h)*8192; B half at 32768+(buf*2+h)*8192.
// Each 16KB half is a linear copy of one Hf/Wf region: frag fr at fr*512+lane*8.
// A frags: fr = i*2+kk (i=0..7 m-frags, kk k-half). B frags: fr = (wc&1)*8+j*2+kk.
// Schedule = R10: stages ph1 b1.A.h0<-T1, ph2 b1.A.h1<-T1, ph3 b0.B.h0<-T0+2,
// ph4 b0.B.h1, ph5 b0.A.h0, ph6 b0.A.h1, ph7 b1.B.h0, ph8 b1.B.h1; VMC(2)
// drains before the closing barrier of ph3/ph7; lgkm(4/8/0) counted.
__global__ __launch_bounds__(512, 2)
void lmhead_gemm_256(const unsigned short* __restrict__ Hf,  // frag-linear bf16
                     const unsigned short* __restrict__ Wf,  // frag-linear bf16
                     const float* __restrict__ bias,
                     float* __restrict__ C)
{
    __shared__ unsigned short lds[65536];  // 128 KB

    const int tid  = threadIdx.x;
    const int bid  = blockIdx.x;
    const int wgid = (bid & 7) * (NWG / 8) + (bid >> 3);  // bijective XCD chunks
    const int mblk = wgid & (MBLKS - 1);                  // M fastest-varying
    const int nblk = wgid >> 3;

    const int lane = tid & 63;
    const int wv   = tid >> 6;     // 0..7
    const int wr   = wv >> 2;      // 0..1 : wave M-half (128 rows)
    const int wc   = wv & 3;       // 0..3 : wave N-slot (64 cols)
    const int l15  = lane & 15;
    const int l4   = lane >> 4;

    const int dstw = (tid & 448) * 8;   // wave-uniform LDS base (wv*512 elems)

    // staging: linear copy of one 16KB fragment region (src contiguous/wave)
#define STAGE_A(u, h, BUF) { \
        const unsigned short* s_ = Hf + ((size_t)((mblk * 2 + (h)) * 64 + (u))) * 8192 + tid * 8; \
        unsigned short* d_ = &lds[(((BUF) * 2 + (h)) * 8192) + dstw]; \
        GLOAD_LDS16(s_, d_); GLOAD_LDS16(s_ + 4096, d_ + 4096); }
#define STAGE_B(u, h, BUF) { \
        const unsigned short* s_ = Wf + ((size_t)((nblk * 2 + (h)) * 64 + (u))) * 8192 + tid * 8; \
        unsigned short* d_ = &lds[32768 + (((BUF) * 2 + (h)) * 8192) + dstw]; \
        GLOAD_LDS16(s_, d_); GLOAD_LDS16(s_ + 4096, d_ + 4096); }

    f32x4 acc[8][4] = {};
    bhalf8 af0[4][2], af1[4][2], bf01[2][2], bf23[2][2];

    // lane-linear reads: frag fr at fr*512 + lane*8 (compile-time ds offsets)
#define READ_AF0(BUF) { \
        const unsigned short* _as = &lds[((BUF) * 2 + wr) * 8192 + lane * 8]; \
        _Pragma("unroll") \
        for (int i = 0; i < 4; ++i) { \
            af0[i][0] = *(const bhalf8*)&_as[(i * 2 + 0) * 512]; \
            af0[i][1] = *(const bhalf8*)&_as[(i * 2 + 1) * 512]; } }
#define READ_AF1(BUF) { \
        const unsigned short* _as = &lds[((BUF) * 2 + wr) * 8192 + lane * 8]; \
        _Pragma("unroll") \
        for (int i = 0; i < 4; ++i) { \
            af1[i][0] = *(const bhalf8*)&_as[((4 + i) * 2 + 0) * 512]; \
            af1[i][1] = *(const bhalf8*)&_as[((4 + i) * 2 + 1) * 512]; } }
#define READ_BF01(BUF) { \
        const unsigned short* _bs = &lds[32768 + ((BUF) * 2 + (wc >> 1)) * 8192 + (wc & 1) * 4096 + lane * 8]; \
        _Pragma("unroll") \
        for (int j = 0; j < 2; ++j) { \
            bf01[j][0] = *(const bhalf8*)&_bs[(j * 2 + 0) * 512]; \
            bf01[j][1] = *(const bhalf8*)&_bs[(j * 2 + 1) * 512]; } }
#define READ_BF23(BUF) { \
        const unsigned short* _bs = &lds[32768 + ((BUF) * 2 + (wc >> 1)) * 8192 + (wc & 1) * 4096 + lane * 8]; \
        _Pragma("unroll") \
        for (int j = 0; j < 2; ++j) { \
            bf23[j][0] = *(const bhalf8*)&_bs[((2 + j) * 2 + 0) * 512]; \
            bf23[j][1] = *(const bhalf8*)&_bs[((2 + j) * 2 + 1) * 512]; } }

#define MFMA8Q(AF, BF, IOFF, JOFF) { \
        _Pragma("unroll") \
        for (int i = 0; i < 4; ++i) \
            _Pragma("unroll") \
            for (int j = 0; j < 2; ++j) \
                _Pragma("unroll") \
                for (int kk = 0; kk < 2; ++kk) \
                    acc[(IOFF) + i][(JOFF) + j] = __builtin_amdgcn_mfma_f32_16x16x32_bf16( \
                        AF[i][kk], BF[j][kk], acc[(IOFF) + i][(JOFF) + j], 0, 0, 0); }

#define SBAR  __builtin_amdgcn_sched_barrier(0)
#define BARR  __builtin_amdgcn_s_barrier()
#define LGKM(n) asm volatile("s_waitcnt lgkmcnt(" #n ")" ::: "memory")
#define VMC(n)  asm volatile("s_waitcnt vmcnt(" #n ")" ::: "memory")
#define PRIO1 __builtin_amdgcn_s_setprio(1)
#define PRIO0 __builtin_amdgcn_s_setprio(0)

    // ---- prologue: tile0 (buf0 A+B) + tile1 B (buf1) = 12 loads ----
    STAGE_A(0, 0, 0); STAGE_A(0, 1, 0);
    STAGE_B(0, 0, 0); STAGE_B(0, 1, 0);
    STAGE_B(1, 0, 1); STAGE_B(1, 1, 1);
    SBAR;
    VMC(4);                      // drain own tile0 loads BEFORE barrier
    SBAR;
    BARR;                        // tile0 published everywhere
    READ_AF0(0); READ_BF01(0);   // 12 reads for ph1's MFMA
    SBAR;

    #pragma unroll 1
    for (int s2 = 0; s2 < NT; s2 += 2) {
        const int T1 = s2 + 1;
        const bool m2 = (s2 + 2) < NT;

        // ===== ph1: read bf23(b0); stage b1.A.h0<-T1; q00(T0) =====
        READ_BF23(0); STAGE_A(T1, 0, 1); SBAR;
        BARR; LGKM(4); SBAR;
        PRIO1; MFMA8Q(af0, bf01, 0, 0); PRIO0; SBAR;
        BARR;
        // ===== ph2: read af1(b0); stage b1.A.h1<-T1; q01(T0) =====
        READ_AF1(0); STAGE_A(T1, 1, 1); SBAR;
        BARR; LGKM(8); SBAR;
        PRIO1; MFMA8Q(af0, bf23, 0, 2); PRIO0; SBAR;
        BARR;
        // ===== ph3: stage b0.B.h0<-T0+2; q10(T0); DRAIN buf1 -> barrier =====
        if (m2) STAGE_B(s2 + 2, 0, 0);
        SBAR;
        BARR; LGKM(0); SBAR;
        PRIO1; MFMA8Q(af1, bf01, 4, 0); PRIO0; SBAR;
        if (m2) { VMC(2); } else { VMC(0); }   // buf1 (T1) fully landed, own part
        SBAR;
        BARR;                                  // buf1 published everywhere
        // ===== ph4: read af0+bf01 (b1,T1); stage b0.B.h1<-T0+2; q11(T0) =====
        READ_AF0(1); READ_BF01(1);
        if (m2) STAGE_B(s2 + 2, 1, 0);
        SBAR;
        BARR; SBAR;                            // af1/bf23 already landed at ph3
        PRIO1; MFMA8Q(af1, bf23, 4, 2); PRIO0; SBAR;
        BARR;
        // ===== ph5: read bf23(b1); stage b0.A.h0<-T0+2; q00(T1) =====
        READ_BF23(1);
        if (m2) STAGE_A(s2 + 2, 0, 0);
        SBAR;
        BARR; LGKM(4); SBAR;
        PRIO1; MFMA8Q(af0, bf01, 0, 0); PRIO0; SBAR;
        BARR;
        // ===== ph6: read af1(b1); stage b0.A.h1<-T0+2; q01(T1) =====
        READ_AF1(1);
        if (m2) STAGE_A(s2 + 2, 1, 0);
        SBAR;
        BARR; LGKM(8); SBAR;
        PRIO1; MFMA8Q(af0, bf23, 0, 2); PRIO0; SBAR;
        BARR;
        // ===== ph7: stage b1.B.h0<-T1+2; q10(T1); DRAIN buf0 -> barrier =====
        if (m2) STAGE_B(T1 + 2, 0, 1);
        SBAR;
        BARR; LGKM(0); SBAR;
        PRIO1; MFMA8Q(af1, bf01, 4, 0); PRIO0; SBAR;
        if (m2) { VMC(2); } else { VMC(0); }   // buf0 (T0+2) fully landed, own part
        SBAR;
        BARR;                                  // buf0 published everywhere
        // ===== ph8: read af0+bf01 (b0,T0+2); stage b1.B.h1<-T1+2; q11(T1) =====
        if (m2) { READ_AF0(0); READ_BF01(0); }
        if (m2) STAGE_B(T1 + 2, 1, 1);
        SBAR;
        BARR; SBAR;                            // af1/bf23 already landed at ph7
        PRIO1; MFMA8Q(af1, bf23, 4, 2); PRIO0; SBAR;
        BARR;
    }

    // ---- epilogue: D map row=(lane>>4)*4+r, col=lane&15 ----
    const size_t crow0 = (size_t)(mblk * BM + wr * 128 + l4 * 4);
    const int    ccol0 = nblk * BN + wc * 64 + l15;
    #pragma unroll
    for (int j = 0; j < 4; ++j) {
        const float bv = bias[ccol0 + j * 16];
        #pragma unroll
        for (int i = 0; i < 8; ++i) {
            const size_t base = (crow0 + (size_t)i * 16) * N_DIM + ccol0 + j * 16;
            #pragma unroll
            for (int r = 0; r < 4; ++r)
                C[base + (size_t)r * N_DIM] = acc[i][j][r] + bv;
        }
    }
#undef STAGE_A
#undef STAGE_B
#undef READ_AF0
#undef READ_AF1
#undef READ_BF01
#undef READ_BF23
#undef MFMA8Q
#undef SBAR
#undef BARR
#undef LGKM
#undef VMC
#undef PRIO1
#undef PRIO0
}

// ---------------- fallback (fp32 inputs, reg-staged 128^2) ----------------
__global__ __launch_bounds__(256, 2)
void lmhead_gemm_f32(const float* __restrict__ A, const float* __restrict__ W,
                     const float* __restrict__ bias, float* __restrict__ C) {
    __shared__ unsigned short As[2][128 * 64];
    __shared__ unsigned short Bs[2][128 * 64];

    const int tid  = threadIdx.x;
    const int bid  = blockIdx.x;
    const int mblk = bid & 15;
    const int nblk = bid >> 4;
    const int st_row = tid >> 3;
    const int st_g   = tid & 7;
    const int lane = tid & 63;
    const int wv   = tid >> 6;
    const int wm   = (wv >> 1) << 6;
    const int wn   = (wv & 1) << 6;
    const int l15  = lane & 15;
    const int l4   = lane >> 4;

    const float* aptr = A + (size_t)(mblk * 128 + st_row) * K_DIM + st_g * 8;
    const float* bptr = W + (size_t)(nblk * 128 + st_row) * K_DIM + st_g * 8;

    f32x4 acc[4][4] = {};
    float4 ra[4][2], rb[4][2];

    #pragma unroll
    for (int s = 0; s < 4; ++s) {
        const float* ap = aptr + (size_t)(s * 32) * K_DIM;
        const float* bp = bptr + (size_t)(s * 32) * K_DIM;
        ra[s][0] = *(const float4*)(ap);   ra[s][1] = *(const float4*)(ap + 4);
        rb[s][0] = *(const float4*)(bp);   rb[s][1] = *(const float4*)(bp + 4);
    }
    #pragma unroll
    for (int s = 0; s < 4; ++s) {
        const int row = s * 32 + st_row;
        const int off = row * 64 + ((st_g ^ (row & 7)) << 3);
        us8 pa, pb;
        #pragma unroll
        for (int j = 0; j < 4; ++j) {
            pa[j] = f2bf_rn(((const float*)&ra[s][0])[j]);
            pa[j + 4] = f2bf_rn(((const float*)&ra[s][1])[j]);
            pb[j] = f2bf_rn(((const float*)&rb[s][0])[j]);
            pb[j + 4] = f2bf_rn(((const float*)&rb[s][1])[j]);
        }
        *(us8*)&As[0][off] = pa;  *(us8*)&Bs[0][off] = pb;
    }
    __syncthreads();

    for (int t = 0; t < 64; ++t) {
        const int cur = t & 1;
        const bool more = (t + 1) < 64;
        if (more) {
            const float* ap = aptr + (size_t)(t + 1) * 64;
            const float* bp = bptr + (size_t)(t + 1) * 64;
            #pragma unroll
            for (int s = 0; s < 4; ++s) {
                ra[s][0] = *(const float4*)(ap + (size_t)(s * 32) * K_DIM);
                ra[s][1] = *(const float4*)(ap + (size_t)(s * 32) * K_DIM + 4);
                rb[s][0] = *(const float4*)(bp + (size_t)(s * 32) * K_DIM);
                rb[s][1] = *(const float4*)(bp + (size_t)(s * 32) * K_DIM + 4);
            }
        }
        const unsigned short* as = As[cur];
        const unsigned short* bs = Bs[cur];
        #pragma unroll
        for (int kk = 0; kk < 2; ++kk) {
            bhalf8 af[4], bfv[4];
            #pragma unroll
            for (int mf = 0; mf < 4; ++mf) {
                const int row = wm + mf * 16 + l15;
                af[mf] = *(const bhalf8*)&as[row * 64 + ((((kk << 2) + l4) ^ (row & 7)) << 3)];
            }
            #pragma unroll
            for (int nf = 0; nf < 4; ++nf) {
                const int row = wn + nf * 16 + l15;
                bfv[nf] = *(const bhalf8*)&bs[row * 64 + ((((kk << 2) + l4) ^ (row & 7)) << 3)];
            }
            #pragma unroll
            for (int mf = 0; mf < 4; ++mf)
                #pragma unroll
                for (int nf = 0; nf < 4; ++nf)
                    acc[mf][nf] = __builtin_amdgcn_mfma_f32_16x16x32_bf16(
                        af[mf], bfv[nf], acc[mf][nf], 0, 0, 0);
        }
        if (more) {
            const int nbuf = cur ^ 1;
            #pragma unroll
            for (int s = 0; s < 4; ++s) {
                const int row = s * 32 + st_row;
                const int off = row * 64 + ((st_g ^ (row & 7)) << 3);
                us8 pa, pb;
                #pragma unroll
                for (int j = 0; j < 4; ++j) {
                    pa[j] = f2bf_rn(((const float*)&ra[s][0])[j]);
                    pa[j + 4] = f2bf_rn(((const float*)&ra[s][1])[j]);
                    pb[j] = f2bf_rn(((const float*)&rb[s][0])[j]);
                    pb[j + 4] = f2bf_rn(((const float*)&rb[s][1])[j]);
                }
                *(us8*)&As[nbuf][off] = pa;  *(us8*)&Bs[nbuf][off] = pb;
            }
        }
        __syncthreads();
    }

    const size_t crow0 = (size_t)(mblk * 128 + wm + l4 * 4);
    const int    ccol0 = nblk * 128 + wn + l15;
    #pragma unroll
    for (int nf = 0; nf < 4; ++nf) {
        const float bv = bias[ccol0 + nf * 16];
        #pragma unroll
        for (int mf = 0; mf < 4; ++mf) {
            const size_t base = (crow0 + (size_t)mf * 16) * N_DIM + ccol0 + nf * 16;
            #pragma unroll
            for (int r = 0; r < 4; ++r)
                C[base + (size_t)r * N_DIM] = acc[mf][nf][r] + bv;
        }
    }
}

extern "C" void kernel_launch(void* const* d_in, const int* in_sizes, int n_in,
                              void* d_out, int out_size, void* d_ws, size_t ws_size,
                              hipStream_t stream) {
    const float* h = (const float*)d_in[0];
    const float* w = (const float*)d_in[1];
    const float* b = (const float*)d_in[2];
    float* out = (float*)d_out;
    // split_num (d_in[3]) is a semantic no-op: K-slices sum to the full GEMM.

    if (ws_size >= WS_NEEDED) {
        unsigned short* wbf = (unsigned short*)d_ws;   // fragment-linear W
        unsigned short* hbf = wbf + W_ELEMS;           // fragment-linear H
        cvt_w_frag<<<2048, 256, 0, stream>>>(w, wbf);
        cvt_h_frag<<<2048, 256, 0, stream>>>(h, hbf);
        lmhead_gemm_256<<<NWG, 512, 0, stream>>>(hbf, wbf, b, out);
    } else {
        lmhead_gemm_f32<<<4000, 256, 0, stream>>>(h, w, b, out);
    }
}

// Round 12
// 627.660 us; speedup vs baseline: 1.0053x; 1.0053x over previous
//
#include <hip/hip_runtime.h>
#include <hip/hip_bf16.h>

// SlicedLMHead: logits[2048][32000] = H[2048][4096] @ W[32000][4096]^T + bias
// Round 12: R11 (fragment-linear LDS, 8-phase/2-tile, read-ahead + counted
// lgkm) with a RE-LEDGERED stage schedule: every half-tile now has >=2 phases
// (>=1300 cyc) between stage-issue and its vmcnt drain (R10/R11 gave A-halves
// only 1-2 phases < loaded HBM latency -> block-wide stalls at both drains).
// Ledger: ph1 B(T1)h1 ph2 A(T1)h1 ph3 B(T0+2)h0 ph4 A(T0+2)h0+VMC(4)
//         ph5 B(T0+2)h1 ph6 A(T0+2)h1 ph7 B(T1+2)h0 ph8 A(T1+2)h0+VMC(4)

typedef __attribute__((ext_vector_type(8))) short bhalf8;   // 8 bf16
typedef __attribute__((ext_vector_type(4))) float f32x4;    // MFMA acc
typedef __attribute__((ext_vector_type(8))) unsigned short us8;

#define M_DIM 2048
#define N_DIM 32000
#define K_DIM 4096
#define BM 256
#define BN 256
#define BK 64
#define NT (K_DIM / BK)       // 64 K-tiles
#define MBLKS (M_DIM / BM)    // 8
#define NBLKS (N_DIM / BN)    // 125
#define NWG (MBLKS * NBLKS)   // 1000, divisible by 8

#define W_ELEMS ((size_t)N_DIM * K_DIM)   // 131,072,000
#define H_ELEMS ((size_t)M_DIM * K_DIM)   // 8,388,608
#define WS_NEEDED ((W_ELEMS + H_ELEMS) * 2)

#define GLOAD_LDS16(g, l) \
    __builtin_amdgcn_global_load_lds( \
        (const __attribute__((address_space(1))) unsigned int*)(g), \
        (__attribute__((address_space(3))) unsigned int*)(l), 16, 0, 0)

__device__ __forceinline__ unsigned short f2bf_rn(float f) {
    unsigned int u = __float_as_uint(f);
    u += 0x7FFFu + ((u >> 16) & 1u);
    return (unsigned short)(u >> 16);
}

// ---------------- W: fp32 -> bf16 fragment-linear ----------------
// chunk c = ((nblk*2 + h)*64 + t)*16 + f, f = wcbit*8 + j*2 + kk
__global__ __launch_bounds__(256)
void cvt_w_frag(const float* __restrict__ w, unsigned short* __restrict__ wn) {
    const int lane = threadIdx.x & 63;
    const int nwav = gridDim.x * 4;
    const int l15  = lane & 15;
    const int l4g  = (lane >> 4) * 8;
    for (int c = blockIdx.x * 4 + (threadIdx.x >> 6); c < 256000; c += nwav) {
        const int f   = c & 15;
        const int t   = (c >> 4) & 63;
        const int hh  = (c >> 10) & 1;
        const int nb  = c >> 11;
        const int kk  = f & 1;
        const int j   = (f >> 1) & 3;
        const int wcb = f >> 3;
        const int row = nb * 256 + hh * 128 + wcb * 64 + j * 16 + l15;
        const int k   = t * 64 + kk * 32 + l4g;
        const float* s = w + (size_t)row * K_DIM + k;
        const float4 v0 = *(const float4*)s;
        const float4 v1 = *(const float4*)(s + 4);
        us8 p;
        p[0] = f2bf_rn(v0.x); p[1] = f2bf_rn(v0.y);
        p[2] = f2bf_rn(v0.z); p[3] = f2bf_rn(v0.w);
        p[4] = f2bf_rn(v1.x); p[5] = f2bf_rn(v1.y);
        p[6] = f2bf_rn(v1.z); p[7] = f2bf_rn(v1.w);
        *(us8*)(wn + (size_t)c * 512 + lane * 8) = p;
    }
}

// ---------------- H: fp32 -> bf16 fragment-linear ----------------
__global__ __launch_bounds__(256)
void cvt_h_frag(const float* __restrict__ h, unsigned short* __restrict__ hn) {
    const int lane = threadIdx.x & 63;
    const int nwav = gridDim.x * 4;
    const int l15  = lane & 15;
    const int l4g  = (lane >> 4) * 8;
    for (int c = blockIdx.x * 4 + (threadIdx.x >> 6); c < 16384; c += nwav) {
        const int f  = c & 15;
        const int t  = (c >> 4) & 63;
        const int hh = (c >> 10) & 1;
        const int mb = c >> 11;
        const int kk = f & 1;
        const int i  = f >> 1;
        const int row = mb * 256 + hh * 128 + i * 16 + l15;
        const int k   = t * 64 + kk * 32 + l4g;
        const float* s = h + (size_t)row * K_DIM + k;
        const float4 v0 = *(const float4*)s;
        const float4 v1 = *(const float4*)(s + 4);
        us8 p;
        p[0] = f2bf_rn(v0.x); p[1] = f2bf_rn(v0.y);
        p[2] = f2bf_rn(v0.z); p[3] = f2bf_rn(v0.w);
        p[4] = f2bf_rn(v1.x); p[5] = f2bf_rn(v1.y);
        p[6] = f2bf_rn(v1.z); p[7] = f2bf_rn(v1.w);
        *(us8*)(hn + (size_t)c * 512 + lane * 8) = p;
    }
}

// ---------------- 256^2 bf16 GEMM, re-ledgered 8-phase / 2-tile ----------------
__global__ __launch_bounds__(512, 2)
void lmhead_gemm_256(const unsigned short* __restrict__ Hf,  // frag-linear bf16
                     const unsigned short* __restrict__ Wf,  // frag-linear bf16
                     const float* __restrict__ bias,
                     float* __restrict__ C)
{
    __shared__ unsigned short lds[65536];  // 128 KB

    const int tid  = threadIdx.x;
    const int bid  = blockIdx.x;
    const int wgid = (bid & 7) * (NWG / 8) + (bid >> 3);  // bijective XCD chunks
    const int mblk = wgid & (MBLKS - 1);                  // M fastest-varying
    const int nblk = wgid >> 3;

    const int lane = tid & 63;
    const int wv   = tid >> 6;     // 0..7
    const int wr   = wv >> 2;      // 0..1 : wave M-half (128 rows)
    const int wc   = wv & 3;       // 0..3 : wave N-slot (64 cols)
    const int l15  = lane & 15;
    const int l4   = lane >> 4;

    const int dstw = (tid & 448) * 8;   // wave-uniform LDS base

#define STAGE_A(u, h, BUF) { \
        const unsigned short* s_ = Hf + ((size_t)((mblk * 2 + (h)) * 64 + (u))) * 8192 + tid * 8; \
        unsigned short* d_ = &lds[(((BUF) * 2 + (h)) * 8192) + dstw]; \
        GLOAD_LDS16(s_, d_); GLOAD_LDS16(s_ + 4096, d_ + 4096); }
#define STAGE_B(u, h, BUF) { \
        const unsigned short* s_ = Wf + ((size_t)((nblk * 2 + (h)) * 64 + (u))) * 8192 + tid * 8; \
        unsigned short* d_ = &lds[32768 + (((BUF) * 2 + (h)) * 8192) + dstw]; \
        GLOAD_LDS16(s_, d_); GLOAD_LDS16(s_ + 4096, d_ + 4096); }

    f32x4 acc[8][4] = {};
    bhalf8 af0[4][2], af1[4][2], bf01[2][2], bf23[2][2];

#define READ_AF0(BUF) { \
        const unsigned short* _as = &lds[((BUF) * 2 + wr) * 8192 + lane * 8]; \
        _Pragma("unroll") \
        for (int i = 0; i < 4; ++i) { \
            af0[i][0] = *(const bhalf8*)&_as[(i * 2 + 0) * 512]; \
            af0[i][1] = *(const bhalf8*)&_as[(i * 2 + 1) * 512]; } }
#define READ_AF1(BUF) { \
        const unsigned short* _as = &lds[((BUF) * 2 + wr) * 8192 + lane * 8]; \
        _Pragma("unroll") \
        for (int i = 0; i < 4; ++i) { \
            af1[i][0] = *(const bhalf8*)&_as[((4 + i) * 2 + 0) * 512]; \
            af1[i][1] = *(const bhalf8*)&_as[((4 + i) * 2 + 1) * 512]; } }
#define READ_BF01(BUF) { \
        const unsigned short* _bs = &lds[32768 + ((BUF) * 2 + (wc >> 1)) * 8192 + (wc & 1) * 4096 + lane * 8]; \
        _Pragma("unroll") \
        for (int j = 0; j < 2; ++j) { \
            bf01[j][0] = *(const bhalf8*)&_bs[(j * 2 + 0) * 512]; \
            bf01[j][1] = *(const bhalf8*)&_bs[(j * 2 + 1) * 512]; } }
#define READ_BF23(BUF) { \
        const unsigned short* _bs = &lds[32768 + ((BUF) * 2 + (wc >> 1)) * 8192 + (wc & 1) * 4096 + lane * 8]; \
        _Pragma("unroll") \
        for (int j = 0; j < 2; ++j) { \
            bf23[j][0] = *(const bhalf8*)&_bs[((2 + j) * 2 + 0) * 512]; \
            bf23[j][1] = *(const bhalf8*)&_bs[((2 + j) * 2 + 1) * 512]; } }

#define MFMA8Q(AF, BF, IOFF, JOFF) { \
        _Pragma("unroll") \
        for (int i = 0; i < 4; ++i) \
            _Pragma("unroll") \
            for (int j = 0; j < 2; ++j) \
                _Pragma("unroll") \
                for (int kk = 0; kk < 2; ++kk) \
                    acc[(IOFF) + i][(JOFF) + j] = __builtin_amdgcn_mfma_f32_16x16x32_bf16( \
                        AF[i][kk], BF[j][kk], acc[(IOFF) + i][(JOFF) + j], 0, 0, 0); }

#define SBAR  __builtin_amdgcn_sched_barrier(0)
#define BARR  __builtin_amdgcn_s_barrier()
#define LGKM(n) asm volatile("s_waitcnt lgkmcnt(" #n ")" ::: "memory")
#define VMC(n)  asm volatile("s_waitcnt vmcnt(" #n ")" ::: "memory")
#define PRIO1 __builtin_amdgcn_s_setprio(1)
#define PRIO0 __builtin_amdgcn_s_setprio(0)

    // ---- prologue: A(0),B(0) full -> buf0; B(1)h0, A(1)h0 -> buf1 (12 loads) ----
    STAGE_A(0, 0, 0); STAGE_A(0, 1, 0);
    STAGE_B(0, 0, 0); STAGE_B(0, 1, 0);
    STAGE_B(1, 0, 1); STAGE_A(1, 0, 1);
    SBAR;
    VMC(4);                      // tile0 drained (own); B(1)h0,A(1)h0 flying
    SBAR;
    BARR;                        // tile0 published
    READ_AF0(0); READ_BF01(0);   // 12 reads for ph1's MFMA
    SBAR;

    #pragma unroll 1
    for (int s2 = 0; s2 < NT; s2 += 2) {
        const int T1 = s2 + 1;
        const bool m2 = (s2 + 2) < NT;

        // ===== ph1: read bf23(b0); stage B(T1)h1->b1; q00(T0) =====
        READ_BF23(0); STAGE_B(T1, 1, 1); SBAR;
        BARR; LGKM(4); SBAR;
        PRIO1; MFMA8Q(af0, bf01, 0, 0); PRIO0; SBAR;
        BARR;
        // ===== ph2: read af1(b0); stage A(T1)h1->b1; q01(T0) =====
        READ_AF1(0); STAGE_A(T1, 1, 1); SBAR;
        BARR; LGKM(8); SBAR;
        PRIO1; MFMA8Q(af0, bf23, 0, 2); PRIO0; SBAR;
        BARR;
        // ===== ph3: stage B(T0+2)h0->b0; q10(T0) =====
        if (m2) STAGE_B(s2 + 2, 0, 0);
        SBAR;
        BARR; LGKM(0); SBAR;
        PRIO1; MFMA8Q(af1, bf01, 4, 0); PRIO0; SBAR;
        BARR;
        // ===== ph4: stage A(T0+2)h0->b0; VMC(4) [T1 landed, leads 2-5ph];
        //            BARR(publish); read af0+bf01(b1); q11(T0) =====
        if (m2) STAGE_A(s2 + 2, 0, 0);
        SBAR;
        if (m2) { VMC(4); } else { VMC(0); }
        SBAR;
        BARR;
        READ_AF0(1); READ_BF01(1); SBAR;
        PRIO1; MFMA8Q(af1, bf23, 4, 2); PRIO0; SBAR;
        BARR;
        // ===== ph5: read bf23(b1); stage B(T0+2)h1->b0; q00(T1) =====
        READ_BF23(1);
        if (m2) STAGE_B(s2 + 2, 1, 0);
        SBAR;
        BARR; LGKM(4); SBAR;
        PRIO1; MFMA8Q(af0, bf01, 0, 0); PRIO0; SBAR;
        BARR;
        // ===== ph6: read af1(b1); stage A(T0+2)h1->b0; q01(T1) =====
        READ_AF1(1);
        if (m2) STAGE_A(s2 + 2, 1, 0);
        SBAR;
        BARR; LGKM(8); SBAR;
        PRIO1; MFMA8Q(af0, bf23, 0, 2); PRIO0; SBAR;
        BARR;
        // ===== ph7: stage B(T1+2)h0->b1; q10(T1) =====
        if (m2) STAGE_B(T1 + 2, 0, 1);
        SBAR;
        BARR; LGKM(0); SBAR;
        PRIO1; MFMA8Q(af1, bf01, 4, 0); PRIO0; SBAR;
        BARR;
        // ===== ph8: stage A(T1+2)h0->b1; VMC(4) [T0+2 landed, leads 2-5ph];
        //            BARR(publish); read af0+bf01(b0,next); q11(T1) =====
        if (m2) STAGE_A(T1 + 2, 0, 1);
        SBAR;
        if (m2) { VMC(4); } else { VMC(0); }
        SBAR;
        BARR;
        if (m2) { READ_AF0(0); READ_BF01(0); }
        SBAR;
        PRIO1; MFMA8Q(af1, bf23, 4, 2); PRIO0; SBAR;
        BARR;
    }

    // ---- epilogue: D map row=(lane>>4)*4+r, col=lane&15 ----
    const size_t crow0 = (size_t)(mblk * BM + wr * 128 + l4 * 4);
    const int    ccol0 = nblk * BN + wc * 64 + l15;
    #pragma unroll
    for (int j = 0; j < 4; ++j) {
        const float bv = bias[ccol0 + j * 16];
        #pragma unroll
        for (int i = 0; i < 8; ++i) {
            const size_t base = (crow0 + (size_t)i * 16) * N_DIM + ccol0 + j * 16;
            #pragma unroll
            for (int r = 0; r < 4; ++r)
                C[base + (size_t)r * N_DIM] = acc[i][j][r] + bv;
        }
    }
#undef STAGE_A
#undef STAGE_B
#undef READ_AF0
#undef READ_AF1
#undef READ_BF01
#undef READ_BF23
#undef MFMA8Q
#undef SBAR
#undef BARR
#undef LGKM
#undef VMC
#undef PRIO1
#undef PRIO0
}

// ---------------- fallback (fp32 inputs, reg-staged 128^2) ----------------
__global__ __launch_bounds__(256, 2)
void lmhead_gemm_f32(const float* __restrict__ A, const float* __restrict__ W,
                     const float* __restrict__ bias, float* __restrict__ C) {
    __shared__ unsigned short As[2][128 * 64];
    __shared__ unsigned short Bs[2][128 * 64];

    const int tid  = threadIdx.x;
    const int bid  = blockIdx.x;
    const int mblk = bid & 15;
    const int nblk = bid >> 4;
    const int st_row = tid >> 3;
    const int st_g   = tid & 7;
    const int lane = tid & 63;
    const int wv   = tid >> 6;
    const int wm   = (wv >> 1) << 6;
    const int wn   = (wv & 1) << 6;
    const int l15  = lane & 15;
    const int l4   = lane >> 4;

    const float* aptr = A + (size_t)(mblk * 128 + st_row) * K_DIM + st_g * 8;
    const float* bptr = W + (size_t)(nblk * 128 + st_row) * K_DIM + st_g * 8;

    f32x4 acc[4][4] = {};
    float4 ra[4][2], rb[4][2];

    #pragma unroll
    for (int s = 0; s < 4; ++s) {
        const float* ap = aptr + (size_t)(s * 32) * K_DIM;
        const float* bp = bptr + (size_t)(s * 32) * K_DIM;
        ra[s][0] = *(const float4*)(ap);   ra[s][1] = *(const float4*)(ap + 4);
        rb[s][0] = *(const float4*)(bp);   rb[s][1] = *(const float4*)(bp + 4);
    }
    #pragma unroll
    for (int s = 0; s < 4; ++s) {
        const int row = s * 32 + st_row;
        const int off = row * 64 + ((st_g ^ (row & 7)) << 3);
        us8 pa, pb;
        #pragma unroll
        for (int j = 0; j < 4; ++j) {
            pa[j] = f2bf_rn(((const float*)&ra[s][0])[j]);
            pa[j + 4] = f2bf_rn(((const float*)&ra[s][1])[j]);
            pb[j] = f2bf_rn(((const float*)&rb[s][0])[j]);
            pb[j + 4] = f2bf_rn(((const float*)&rb[s][1])[j]);
        }
        *(us8*)&As[0][off] = pa;  *(us8*)&Bs[0][off] = pb;
    }
    __syncthreads();

    for (int t = 0; t < 64; ++t) {
        const int cur = t & 1;
        const bool more = (t + 1) < 64;
        if (more) {
            const float* ap = aptr + (size_t)(t + 1) * 64;
            const float* bp = bptr + (size_t)(t + 1) * 64;
            #pragma unroll
            for (int s = 0; s < 4; ++s) {
                ra[s][0] = *(const float4*)(ap + (size_t)(s * 32) * K_DIM);
                ra[s][1] = *(const float4*)(ap + (size_t)(s * 32) * K_DIM + 4);
                rb[s][0] = *(const float4*)(bp + (size_t)(s * 32) * K_DIM);
                rb[s][1] = *(const float4*)(bp + (size_t)(s * 32) * K_DIM + 4);
            }
        }
        const unsigned short* as = As[cur];
        const unsigned short* bs = Bs[cur];
        #pragma unroll
        for (int kk = 0; kk < 2; ++kk) {
            bhalf8 af[4], bfv[4];
            #pragma unroll
            for (int mf = 0; mf < 4; ++mf) {
                const int row = wm + mf * 16 + l15;
                af[mf] = *(const bhalf8*)&as[row * 64 + ((((kk << 2) + l4) ^ (row & 7)) << 3)];
            }
            #pragma unroll
            for (int nf = 0; nf < 4; ++nf) {
                const int row = wn + nf * 16 + l15;
                bfv[nf] = *(const bhalf8*)&bs[row * 64 + ((((kk << 2) + l4) ^ (row & 7)) << 3)];
            }
            #pragma unroll
            for (int mf = 0; mf < 4; ++mf)
                #pragma unroll
                for (int nf = 0; nf < 4; ++nf)
                    acc[mf][nf] = __builtin_amdgcn_mfma_f32_16x16x32_bf16(
                        af[mf], bfv[nf], acc[mf][nf], 0, 0, 0);
        }
        if (more) {
            const int nbuf = cur ^ 1;
            #pragma unroll
            for (int s = 0; s < 4; ++s) {
                const int row = s * 32 + st_row;
                const int off = row * 64 + ((st_g ^ (row & 7)) << 3);
                us8 pa, pb;
                #pragma unroll
                for (int j = 0; j < 4; ++j) {
                    pa[j] = f2bf_rn(((const float*)&ra[s][0])[j]);
                    pa[j + 4] = f2bf_rn(((const float*)&ra[s][1])[j]);
                    pb[j] = f2bf_rn(((const float*)&rb[s][0])[j]);
                    pb[j + 4] = f2bf_rn(((const float*)&rb[s][1])[j]);
                }
                *(us8*)&As[nbuf][off] = pa;  *(us8*)&Bs[nbuf][off] = pb;
            }
        }
        __syncthreads();
    }

    const size_t crow0 = (size_t)(mblk * 128 + wm + l4 * 4);
    const int    ccol0 = nblk * 128 + wn + l15;
    #pragma unroll
    for (int nf = 0; nf < 4; ++nf) {
        const float bv = bias[ccol0 + nf * 16];
        #pragma unroll
        for (int mf = 0; mf < 4; ++mf) {
            const size_t base = (crow0 + (size_t)mf * 16) * N_DIM + ccol0 + nf * 16;
            #pragma unroll
            for (int r = 0; r < 4; ++r)
                C[base + (size_t)r * N_DIM] = acc[mf][nf][r] + bv;
        }
    }
}

extern "C" void kernel_launch(void* const* d_in, const int* in_sizes, int n_in,
                              void* d_out, int out_size, void* d_ws, size_t ws_size,
                              hipStream_t stream) {
    const float* h = (const float*)d_in[0];
    const float* w = (const float*)d_in[1];
    const float* b = (const float*)d_in[2];
    float* out = (float*)d_out;
    // split_num (d_in[3]) is a semantic no-op: K-slices sum to the full GEMM.

    if (ws_size >= WS_NEEDED) {
        unsigned short* wbf = (unsigned short*)d_ws;   // fragment-linear W
        unsigned short* hbf = wbf + W_ELEMS;           // fragment-linear H
        cvt_w_frag<<<2048, 256, 0, stream>>>(w, wbf);
        cvt_h_frag<<<2048, 256, 0, stream>>>(h, hbf);
        lmhead_gemm_256<<<NWG, 512, 0, stream>>>(hbf, wbf, b, out);
    } else {
        lmhead_gemm_f32<<<4000, 256, 0, stream>>>(h, w, b, out);
    }
}